// Round 6
// baseline (142.927 us; speedup 1.0000x reference)
//
#include <hip/hip_runtime.h>
#include <hip/hip_bf16.h>

// Problem constants (from reference): B=2, C=3, H=W=64, N=4096.
namespace {
constexpr int BB = 2;
constexpr int NN = 4096;

// Workspace layout. Small fp32 arrays first (element offsets in floats):
constexpr int OFF_SRC4 = 0;             // float4[B*N]
constexpr int OFF_TAR4 = 4 * BB * NN;   // float4[B*N]
constexpr int OFF_U4   = 8 * BB * NN;   // float4[B*N] (ux,uy,uz,|u|^2)
constexpr int OFF_W4   = 12 * BB * NN;  // float4[B*N] normalized diff dir
constexpr int OFF_RINV = 16 * BB * NN;  // float[B*N]  1/den_i (row softmax)
constexpr int OFF_CS   = 17 * BB * NN;  // float[B*N]  column S accumulators (zeroed)
constexpr int OFF_NMAX = 18 * BB * NN;  // float[B]    max|src| (zeroed, after CS!)
// fp16 N x N streams (byte offsets):
constexpr size_t OFF_E1B = (size_t)1 << 20;                       // e_ij  (row weights numer)
constexpr size_t NHALF   = (size_t)BB * NN * NN;                  // 33.55M elements
constexpr size_t OFF_E2B = OFF_E1B + NHALF * 2;                   // E_ij  (col softmax numer)
constexpr float L2E = 1.4426950408889634f;   // log2(e)
constexpr float S50 = 72.13475204444817f;    // 50 * log2(e)
constexpr float BIAS = 10.0f;                // fp16 underflow headroom for E
}

__device__ __forceinline__ float fsqrt(float x) { return __builtin_amdgcn_sqrtf(x); }
__device__ __forceinline__ float ex2(float x) { return __builtin_amdgcn_exp2f(x); }
__device__ __forceinline__ float frcp(float x) { return __builtin_amdgcn_rcpf(x); }

// ---------------------------------------------------------------------------
// Setup: per-batch M = K R K^-1, o = K t; per-pixel fp32 arrays; max|src| per b.
// ---------------------------------------------------------------------------
__global__ __launch_bounds__(256) void k_setup(
    const float* __restrict__ fsrc, const float* __restrict__ ftar,
    const float* __restrict__ Kb, const float* __restrict__ Rb,
    const float* __restrict__ tb, float* __restrict__ ws) {
  int gid = blockIdx.x * blockDim.x + threadIdx.x;
  if (gid >= BB * NN) return;
  int b = gid >> 12;
  int n = gid & (NN - 1);

  float K[9], R[9], t3[3];
#pragma unroll
  for (int k = 0; k < 9; k++) { K[k] = Kb[b * 9 + k]; R[k] = Rb[b * 9 + k]; }
#pragma unroll
  for (int k = 0; k < 3; k++) t3[k] = tb[b * 3 + k];

  float c00 = K[4] * K[8] - K[5] * K[7];
  float c01 = K[5] * K[6] - K[3] * K[8];
  float c02 = K[3] * K[7] - K[4] * K[6];
  float det = K[0] * c00 + K[1] * c01 + K[2] * c02;
  float id = 1.0f / det;
  float Ki[9];
  Ki[0] = c00 * id; Ki[1] = (K[2] * K[7] - K[1] * K[8]) * id; Ki[2] = (K[1] * K[5] - K[2] * K[4]) * id;
  Ki[3] = c01 * id; Ki[4] = (K[0] * K[8] - K[2] * K[6]) * id; Ki[5] = (K[2] * K[3] - K[0] * K[5]) * id;
  Ki[6] = c02 * id; Ki[7] = (K[1] * K[6] - K[0] * K[7]) * id; Ki[8] = (K[0] * K[4] - K[1] * K[3]) * id;

  float RK[9];
#pragma unroll
  for (int i = 0; i < 3; i++)
#pragma unroll
    for (int j = 0; j < 3; j++)
      RK[i * 3 + j] = R[i * 3 + 0] * Ki[j] + R[i * 3 + 1] * Ki[3 + j] + R[i * 3 + 2] * Ki[6 + j];
  float M3[9];
#pragma unroll
  for (int i = 0; i < 3; i++)
#pragma unroll
    for (int j = 0; j < 3; j++)
      M3[i * 3 + j] = K[i * 3 + 0] * RK[j] + K[i * 3 + 1] * RK[3 + j] + K[i * 3 + 2] * RK[6 + j];
  float o0 = K[0] * t3[0] + K[1] * t3[1] + K[2] * t3[2];
  float o1 = K[3] * t3[0] + K[4] * t3[1] + K[5] * t3[2];
  float o2 = K[6] * t3[0] + K[7] * t3[1] + K[8] * t3[2];

  float sx = fsrc[b * 3 * NN + 0 * NN + n];
  float sy = fsrc[b * 3 * NN + 1 * NN + n];
  float sz = fsrc[b * 3 * NN + 2 * NN + n];
  float tx = ftar[b * 3 * NN + 0 * NN + n];
  float ty = ftar[b * 3 * NN + 1 * NN + n];
  float tz = ftar[b * 3 * NN + 2 * NN + n];

  float ux = sx - o0, uy = sy - o1, uz = sz - o2;
  float usq = ux * ux + uy * uy + uz * uz;

  float px = (float)(n >> 6), py = (float)(n & 63);
  float vx = M3[0] * px + M3[1] * py + M3[2];
  float vy = M3[3] * px + M3[4] * py + M3[5];
  float vz = M3[6] * px + M3[7] * py + M3[8];
  float invn = rsqrtf(vx * vx + vy * vy + vz * vz);

  float4* src4 = (float4*)(ws + OFF_SRC4);
  float4* tar4 = (float4*)(ws + OFF_TAR4);
  float4* u4 = (float4*)(ws + OFF_U4);
  float4* w4 = (float4*)(ws + OFF_W4);
  src4[gid] = make_float4(sx, sy, sz, 0.f);
  tar4[gid] = make_float4(tx, ty, tz, 0.f);
  u4[gid] = make_float4(ux, uy, uz, usq);
  w4[gid] = make_float4(vx * invn, vy * invn, vz * invn, 0.f);

  float ns = fsqrt(sx * sx + sy * sy + sz * sz);
#pragma unroll
  for (int off = 32; off; off >>= 1) ns = fmaxf(ns, __shfl_xor(ns, off));
  if ((threadIdx.x & 63) == 0)
    atomicMax((unsigned int*)(ws + OFF_NMAX + b), __float_as_uint(ns));
}

// ---------------------------------------------------------------------------
// Pass 1: row softmax over j (exp2 domain). Block = 4 waves on 8 rows,
// j split 4 ways. Loop A: true max d2 (cheap, no trans). Loop B: e_ij =
// exp2(t2 - m2) summed for den and STORED as fp16 for pass2.
// e layout: e[(global_row)*NN + j_local].
// ---------------------------------------------------------------------------
__global__ __launch_bounds__(256, 4) void k_pass1(float* __restrict__ ws) {
  __shared__ float sred[4][8];
  const float4* u4 = (const float4*)(ws + OFF_U4);
  const float4* w4 = (const float4*)(ws + OFF_W4);
  float* rinv = ws + OFF_RINV;
  _Float16* eh = (_Float16*)((char*)ws + OFF_E1B);
  int tid = threadIdx.x, wid = tid >> 6, lane = tid & 63;
  int g0 = blockIdx.x * 8;
  int b = g0 >> 12;

  float ux[8], uy[8], uz[8], us[8];
#pragma unroll
  for (int r = 0; r < 8; r++) {
    float4 u = u4[g0 + r];
    ux[r] = u.x; uy[r] = u.y; uz[r] = u.z; us[r] = u.w;
  }
  const float4* wb = w4 + b * NN;

  // Loop A: max d2
  float mx[8] = {0.f, 0.f, 0.f, 0.f, 0.f, 0.f, 0.f, 0.f};
  for (int j = wid * 64 + lane; j < NN; j += 256) {
    float4 w = wb[j];
#pragma unroll
    for (int r = 0; r < 8; r++) {
      float dot = ux[r] * w.x + uy[r] * w.y + uz[r] * w.z;
      mx[r] = fmaxf(mx[r], us[r] - dot * dot);
    }
  }
#pragma unroll
  for (int off = 32; off; off >>= 1)
#pragma unroll
    for (int r = 0; r < 8; r++) mx[r] = fmaxf(mx[r], __shfl_xor(mx[r], off));
  if (lane == 0) {
#pragma unroll
    for (int r = 0; r < 8; r++) sred[wid][r] = mx[r];
  }
  __syncthreads();
  float m2[8];
#pragma unroll
  for (int r = 0; r < 8; r++)
    m2[r] = S50 * fsqrt(fmaxf(fmaxf(sred[0][r], sred[1][r]), fmaxf(sred[2][r], sred[3][r])));
  __syncthreads();

  // Loop B: den sum + fp16 store of e
  float s[8] = {0.f, 0.f, 0.f, 0.f, 0.f, 0.f, 0.f, 0.f};
  for (int j = wid * 64 + lane; j < NN; j += 256) {
    float4 w = wb[j];
#pragma unroll
    for (int r = 0; r < 8; r++) {
      float dot = ux[r] * w.x + uy[r] * w.y + uz[r] * w.z;
      float d2 = fmaxf(us[r] - dot * dot, 0.f);
      float t = fsqrt(d2);
      float ev = ex2(fmaf(S50, t, -m2[r]));
      s[r] += ev;
      eh[(size_t)(g0 + r) * NN + j] = (_Float16)ev;
    }
  }
#pragma unroll
  for (int off = 32; off; off >>= 1)
#pragma unroll
    for (int r = 0; r < 8; r++) s[r] += __shfl_xor(s[r], off);
  if (lane == 0) {
#pragma unroll
    for (int r = 0; r < 8; r++) sred[wid][r] = s[r];
  }
  __syncthreads();
  if (tid < 8) {
    float tot = sred[0][tid] + sred[1][tid] + sred[2][tid] + sred[3][tid];
    rinv[g0 + tid] = 1.f / tot;
  }
}

// ---------------------------------------------------------------------------
// Pass 2: column softmax numerators + denominators. Lane <-> column layout:
// wave owns 64 consecutive columns, loops i. Per-i data is wave-uniform
// (scalar loads). E_ij = exp2(A'*wgt + BIAS - Mb2_j) stored fp16; S_j
// accumulated via LDS + one atomicAdd per column per block.
// E layout: E[(global_row)*NN + j_local]. Grid: 128 col-groups x 16 i-chunks.
// ---------------------------------------------------------------------------
__global__ __launch_bounds__(256, 8) void k_pass2(float* __restrict__ ws) {
  __shared__ float sS[4][64];
  const float4* src4 = (const float4*)(ws + OFF_SRC4);
  const float4* tar4 = (const float4*)(ws + OFF_TAR4);
  const float* rinv = ws + OFF_RINV;
  float* CS = ws + OFF_CS;
  const _Float16* eh = (const _Float16*)((char*)ws + OFF_E1B);
  _Float16* Eh = (_Float16*)((char*)ws + OFF_E2B);

  int tid = threadIdx.x, wid = tid >> 6, lane = tid & 63;
  int g = blockIdx.x >> 4;        // col-group 0..127
  int c = blockIdx.x & 15;        // i-chunk 0..15
  int gc = g * 64 + lane;         // global column index (b*N + j_local)
  int b = gc >> 12;
  int base = b * NN;
  int jloc = gc - base;
  float maxns = ws[OFF_NMAX + b];

  float4 tt = tar4[gc];
  float Cj = BIAS - maxns * L2E * fsqrt(tt.x * tt.x + tt.y * tt.y + tt.z * tt.z);
  float txl = tt.x * L2E, tyl = tt.y * L2E, tzl = tt.z * L2E;

  float S = 0.f;
  int i0 = c * 256 + wid * 64;
#pragma unroll 4
  for (int it = 0; it < 64; ++it) {
    int i = i0 + it;                       // wave-uniform local row
    float4 sv = src4[base + i];            // uniform (scalar load)
    float invd = rinv[base + i];           // uniform
    float ev = (float)eh[(size_t)(base + i) * NN + jloc];
    float wgt = fmaf(-ev, invd, 1.f);
    float Ap = sv.x * txl + sv.y * tyl + sv.z * tzl;
    float Ev = ex2(fmaf(Ap, wgt, Cj));
    S += Ev;
    Eh[(size_t)(base + i) * NN + jloc] = (_Float16)Ev;
  }
  sS[wid][lane] = S;
  __syncthreads();
  if (wid == 0) {
    float tot = sS[0][lane] + sS[1][lane] + sS[2][lane] + sS[3][lane];
    atomicAdd(&CS[gc], tot);
  }
}

// ---------------------------------------------------------------------------
// Pass 3: out[i,c] = sum_j (E_ij / S_j) * src_j. Block = 4 waves on 4 rows,
// j split 4 ways. No transcendentals; pure fp16-load + FMA stream.
// ---------------------------------------------------------------------------
__global__ __launch_bounds__(256, 8) void k_pass3(const float* __restrict__ ws,
                                                  float* __restrict__ out) {
  __shared__ float sacc[4][12];
  const float4* src4 = (const float4*)(ws + OFF_SRC4);
  const float* CS = ws + OFF_CS;
  const _Float16* Eh = (const _Float16*)((const char*)ws + OFF_E2B);
  int tid = threadIdx.x, wid = tid >> 6, lane = tid & 63;
  int g0 = blockIdx.x * 4;
  int b = g0 >> 12;
  int base = b * NN;

  float acc[4][3];
#pragma unroll
  for (int r = 0; r < 4; r++) { acc[r][0] = 0.f; acc[r][1] = 0.f; acc[r][2] = 0.f; }

#pragma unroll 2
  for (int j = wid * 64 + lane; j < NN; j += 256) {
    float4 sj = src4[base + j];
    float invS = frcp(CS[base + j]);
#pragma unroll
    for (int r = 0; r < 4; r++) {
      float Ev = (float)Eh[(size_t)(g0 + r) * NN + j];
      float p = Ev * invS;
      acc[r][0] += p * sj.x;
      acc[r][1] += p * sj.y;
      acc[r][2] += p * sj.z;
    }
  }
#pragma unroll
  for (int off = 32; off; off >>= 1)
#pragma unroll
    for (int r = 0; r < 4; r++) {
      acc[r][0] += __shfl_xor(acc[r][0], off);
      acc[r][1] += __shfl_xor(acc[r][1], off);
      acc[r][2] += __shfl_xor(acc[r][2], off);
    }
  if (lane == 0) {
#pragma unroll
    for (int r = 0; r < 4; r++) {
      sacc[wid][r * 3 + 0] = acc[r][0];
      sacc[wid][r * 3 + 1] = acc[r][1];
      sacc[wid][r * 3 + 2] = acc[r][2];
    }
  }
  __syncthreads();
  if (tid < 12) {
    float v = sacc[0][tid] + sacc[1][tid] + sacc[2][tid] + sacc[3][tid];
    out[g0 * 3 + tid] = v;
  }
}

extern "C" void kernel_launch(void* const* d_in, const int* in_sizes, int n_in,
                              void* d_out, int out_size, void* d_ws, size_t ws_size,
                              hipStream_t stream) {
  (void)in_sizes; (void)n_in; (void)out_size; (void)ws_size;
  const float* ftar = (const float*)d_in[0];
  const float* fsrc = (const float*)d_in[1];
  const float* K = (const float*)d_in[2];
  const float* R = (const float*)d_in[3];
  const float* t = (const float*)d_in[4];
  float* ws = (float*)d_ws;
  float* out = (float*)d_out;

  // zero the column-S accumulators + per-batch norm-max (contiguous region)
  hipMemsetAsync((char*)d_ws + (size_t)OFF_CS * sizeof(float), 0,
                 (size_t)(BB * NN + BB) * sizeof(float), stream);

  k_setup<<<dim3((BB * NN + 255) / 256), dim3(256), 0, stream>>>(fsrc, ftar, K, R, t, ws);
  k_pass1<<<dim3(1024), dim3(256), 0, stream>>>(ws);
  k_pass2<<<dim3(2048), dim3(256), 0, stream>>>(ws);
  k_pass3<<<dim3(2048), dim3(256), 0, stream>>>(ws, out);
}